// Round 9
// baseline (149.405 us; speedup 1.0000x reference)
//
#include <hip/hip_runtime.h>
#include <hip/hip_bf16.h>
#include <math.h>

#define BSZ 4096
#define DSZ 1024
#define BM  256
#define BN  256
#define BK  64
#define NT  16          // K-tiles
#define NIT 8           // iterations, 2 K-tiles each

typedef unsigned short u16;
typedef __attribute__((ext_vector_type(8))) short bf16x8;   // 8 bf16 = 4 VGPRs
typedef __attribute__((ext_vector_type(4))) float f32x4;    // mfma 16x16 accum

__device__ inline u16 f2bf_rne(float f) {
    unsigned int u = __float_as_uint(f);
    u += 0x7fffu + ((u >> 16) & 1u);      // round-to-nearest-even
    return (u16)(u >> 16);
}

// ---------------------------------------------------------------------------
// Kernel 1: fp32 -> bf16 + exact fp32 row norms. ONE WAVE PER ROW (no
// block reduce, no __syncthreads). 8192 rows -> 2048 blocks x 4 waves.
// Lane j of a wave covers elems {c*256 + j*4 .. +3}, c=0..3 (coalesced 16B).
// Also zeroes rowsum[] (ws is poisoned 0xAA before every launch).
// ---------------------------------------------------------------------------
__global__ __launch_bounds__(256) void cvt_norm_kernel(
        const float* __restrict__ img, const float* __restrict__ txt,
        u16* __restrict__ imgb, u16* __restrict__ txtb,
        float* __restrict__ img_sq, float* __restrict__ txt_sq,
        float* __restrict__ rowsum) {
    const int wid  = blockIdx.x * 4 + (threadIdx.x >> 6);   // 0..8191
    const int lane = threadIdx.x & 63;
    const bool isTxt = (wid >= BSZ);
    const int row = isTxt ? wid - BSZ : wid;

    const float* __restrict__ src = (isTxt ? txt : img) + (size_t)row * DSZ;
    u16* __restrict__ dst = (isTxt ? txtb : imgb) + (size_t)row * DSZ;

    float s = 0.0f;
    #pragma unroll
    for (int c = 0; c < 4; ++c) {
        const float4 v = *reinterpret_cast<const float4*>(src + c * 256 + lane * 4);
        ushort4 o;
        o.x = f2bf_rne(v.x); o.y = f2bf_rne(v.y);
        o.z = f2bf_rne(v.z); o.w = f2bf_rne(v.w);
        *reinterpret_cast<ushort4*>(dst + c * 256 + lane * 4) = o;
        s += v.x * v.x + v.y * v.y + v.z * v.z + v.w * v.w;
    }
    #pragma unroll
    for (int off = 32; off; off >>= 1) s += __shfl_xor(s, off);

    if (lane == 0) {
        if (isTxt) txt_sq[row] = s;
        else { img_sq[row] = s; rowsum[row] = 0.0f; }
    }
}

// ---------------------------------------------------------------------------
// Kernel 2: 256x256 bf16 MFMA cross-GEMM, 8-phase counted-vmcnt schedule with
// REGISTER FRAG PREFETCH (next phase's ds_reads overlap this phase's MFMA),
// fused dist/exp/row-sum epilogue. 512 thr = 8 waves (2M x 4N); per-wave
// 128x64 output = acc[8][4]. Grid 16x16 = 1 block/CU.
//
// LDS 128 KB: A[buf2][half2][128 rows][8 chunks x 16B] @0, B same @65536.
// Tile parity == buffer parity. Swizzle (T2, rule #21): stored chunk s holds
// global chunk s^(row&7); read XORs the same. Verified: 0 conflicts, absmax 0.
//
// Stage schedule (earliest slot-free), iteration i (tiles t0=2i, t1=2i+1):
//   p0: A(2i+1).h1   p1: B(2i+2) [4 loads]   p2: A(2i+2).h0
//   p4: A(2i+2).h1   p5: B(2i+3) [4 loads]   p6: A(2i+3).h0
// Frag prefetch: phase p issues ds_reads for phase p+1 (afr ping-pong by
// (p+1)&1; bfr[2] by tile parity, 8 B-reads at p=3,7). lgkm wait before MFMA
// is COUNTED (4 or 12 = the newer prefetch reads), not 0.
// Guards: vmcnt(8) at end of every even phase (hand-simulated: each staged
// half-tile is guarded >=1 phase before its prefetch-read; last iter {8,2,0}).
// ---------------------------------------------------------------------------
__global__ __launch_bounds__(512, 2) void fused_mfma_kernel(
        const u16* __restrict__ imgb, const u16* __restrict__ txtb,
        const float* __restrict__ img_sq, const float* __restrict__ txt_sq,
        float* __restrict__ rowsum, float* __restrict__ diag_dist) {

    extern __shared__ char smem[];           // 131072 bytes

    const int lin = blockIdx.y * 16 + blockIdx.x;
    const int sw  = (lin & 7) * 32 + (lin >> 3);   // bijective XCD swizzle
    const int bi = sw >> 4, bj = sw & 15;

    const int tid  = threadIdx.x;
    const int lane = tid & 63;
    const int w    = tid >> 6;               // wave 0..7
    const int wr   = w >> 2;                 // 0..1  M-half
    const int wc   = w & 3;                  // 0..3  N-quarter
    const int lr   = lane >> 4;              // 0..3
    const int lc   = lane & 15;
    const int swz  = lc & 7;                 // == row&7 for rows m*16+lc

    const int ib0 = bi * BM;
    const int jb0 = bj * BN;

    auto stageHT = [&](int mat, int kt, int h) {   // one half-tile: 2 loads/thr
        const u16* base   = mat ? txtb : imgb;
        const int rowbase = mat ? jb0 : ib0;
        const int xoff    = mat ? 65536 : 0;
        const int b = kt & 1;
        #pragma unroll
        for (int j = 0; j < 2; ++j) {
            const int row_h = j * 64 + (tid >> 3);        // 0..127 within half
            const int gch   = (tid & 7) ^ (row_h & 7);    // pre-swizzled src
            const u16* g = base + (size_t)(rowbase + h * 128 + row_h) * DSZ
                                + kt * BK + gch * 8;
            char* dst = smem + xoff + b * 32768 + h * 16384 + j * 8192 + w * 1024;
            __builtin_amdgcn_global_load_lds(
                (const __attribute__((address_space(1))) void*)g,
                (__attribute__((address_space(3))) void*)dst, 16, 0, 0);
        }
    };
    auto stageB = [&](int kt) { stageHT(1, kt, 0); stageHT(1, kt, 1); };

    const char* Ab[2] = { smem + wr * 16384,
                          smem + 32768 + wr * 16384 };
    const char* Bb[2] = { smem + 65536 + (wc >> 1) * 16384,
                          smem + 65536 + 32768 + (wc >> 1) * 16384 };
    const int rboff = (wc & 1) * 64;

    // ---- prologue: 14 loads, wait to 8 (B0 + A0h0 landed) ----
    stageB(0);                 // 4
    stageHT(0, 0, 0);          // 2
    stageHT(0, 0, 1);          // 2
    stageB(1);                 // 4
    stageHT(0, 1, 0);          // 2
    asm volatile("s_waitcnt vmcnt(8)" ::: "memory");
    __builtin_amdgcn_s_barrier();

    f32x4 acc[8][4] = {};
    bf16x8 bfr[2][2][4];       // [tile parity][kk][n]
    bf16x8 afr[2][2][2];       // [phase parity][dm][kk]

    // phase-0 fragments (consumed by i0/p0's MFMA; lgkm-waited there)
    #pragma unroll
    for (int kk = 0; kk < 2; ++kk)
        #pragma unroll
        for (int n = 0; n < 4; ++n)
            bfr[0][kk][n] = *reinterpret_cast<const bf16x8*>(
                Bb[0] + (rboff + n * 16 + lc) * 128 + (((kk * 4 + lr) ^ swz) * 16));
    #pragma unroll
    for (int dm = 0; dm < 2; ++dm)
        #pragma unroll
        for (int kk = 0; kk < 2; ++kk)
            afr[0][dm][kk] = *reinterpret_cast<const bf16x8*>(
                Ab[0] + ((dm) * 16 + lc) * 128 + (((kk * 4 + lr) ^ swz) * 16));

    for (int i = 0; i < NIT; ++i) {
        const bool more = (i < NIT - 1);
        #pragma unroll
        for (int p = 0; p < 8; ++p) {
            const int tsel = p >> 2;             // tile of the pair (this phase)
            const int q    = p & 3;              // m-quadrant
            const int np   = (p + 1) & 7;        // next phase
            const int nq   = np & 3;
            const int ntsel = (p < 7) ? (np >> 2) : 0;
            const int nset  = (p + 1) & 1;
            const bool last_phase = (!more) && (p == 7);

            // ---- prefetch next phase's fragments (overlaps this MFMA) ----
            if (!last_phase) {
                if (nq == 0) {
                    #pragma unroll
                    for (int kk = 0; kk < 2; ++kk)
                        #pragma unroll
                        for (int n = 0; n < 4; ++n)
                            bfr[ntsel][kk][n] = *reinterpret_cast<const bf16x8*>(
                                Bb[ntsel] + (rboff + n * 16 + lc) * 128
                                          + (((kk * 4 + lr) ^ swz) * 16));
                }
                #pragma unroll
                for (int dm = 0; dm < 2; ++dm)
                    #pragma unroll
                    for (int kk = 0; kk < 2; ++kk)
                        afr[nset][dm][kk] = *reinterpret_cast<const bf16x8*>(
                            Ab[ntsel] + ((nq * 2 + dm) * 16 + lc) * 128
                                      + (((kk * 4 + lr) ^ swz) * 16));
            }

            // ---- stage (earliest-slot-free schedule) ----
            if (p == 0)      stageHT(0, 2 * i + 1, 1);
            else if (p == 1) { if (more) stageB(2 * i + 2); }
            else if (p == 2) { if (more) stageHT(0, 2 * i + 2, 0); }
            else if (p == 4) { if (more) stageHT(0, 2 * i + 2, 1); }
            else if (p == 5) { if (more) stageB(2 * i + 3); }
            else if (p == 6) { if (more) stageHT(0, 2 * i + 3, 0); }

            __builtin_amdgcn_sched_barrier(0);   // pin prefetch+stage issue here
            __builtin_amdgcn_s_barrier();

            // counted lgkm: wait for THIS phase's frags; next-phase reads stay
            if (last_phase)   asm volatile("s_waitcnt lgkmcnt(0)"  ::: "memory");
            else if (nq == 0) asm volatile("s_waitcnt lgkmcnt(12)" ::: "memory");
            else              asm volatile("s_waitcnt lgkmcnt(4)"  ::: "memory");
            __builtin_amdgcn_sched_barrier(0);   // rule #18

            __builtin_amdgcn_s_setprio(1);
            #pragma unroll
            for (int dm = 0; dm < 2; ++dm)
                #pragma unroll
                for (int n = 0; n < 4; ++n)
                    #pragma unroll
                    for (int kk = 0; kk < 2; ++kk)
                        acc[q * 2 + dm][n] = __builtin_amdgcn_mfma_f32_16x16x32_bf16(
                            afr[p & 1][dm][kk], bfr[tsel][kk][n],
                            acc[q * 2 + dm][n], 0, 0, 0);
            __builtin_amdgcn_s_setprio(0);

            // ---- counted guards on even phases ----
            if ((p & 1) == 0) {
                if (more || p == 0)
                    asm volatile("s_waitcnt vmcnt(8)" ::: "memory");
                else if (p == 2)
                    asm volatile("s_waitcnt vmcnt(2)" ::: "memory");
                else
                    asm volatile("s_waitcnt vmcnt(0)" ::: "memory");
            }
            __builtin_amdgcn_s_barrier();
        }
    }

    // ---- epilogue: dist -> sim -> row partial sums + diagonal ----
    const int jw = jb0 + wc * 64;            // wave's first text col
    const int iw = ib0 + wr * 128;           // wave's first image row

    float tq[4];
    #pragma unroll
    for (int n = 0; n < 4; ++n) tq[n] = txt_sq[jw + n * 16 + lc];

    float rs[8][4];
    #pragma unroll
    for (int m = 0; m < 8; ++m) {
        #pragma unroll
        for (int j = 0; j < 4; ++j) {
            const int gi = iw + m * 16 + lr * 4 + j;
            const float iq = img_sq[gi];
            float s = 0.0f;
            #pragma unroll
            for (int n = 0; n < 4; ++n) {
                const float d2 = iq + tq[n] - 2.0f * acc[m][n][j];
                const float d  = sqrtf(fmaxf(d2, 0.0f));
                const float sim = __expf(-20.0f * d);
                s += sim;
                if (gi == jw + n * 16 + lc) diag_dist[gi] = d;
            }
            rs[m][j] = s;
        }
    }

    #pragma unroll
    for (int off = 1; off < 16; off <<= 1)
        #pragma unroll
        for (int m = 0; m < 8; ++m)
            #pragma unroll
            for (int j = 0; j < 4; ++j)
                rs[m][j] += __shfl_xor(rs[m][j], off);

    if (lc == 0) {
        #pragma unroll
        for (int m = 0; m < 8; ++m)
            #pragma unroll
            for (int j = 0; j < 4; ++j)
                atomicAdd(&rowsum[iw + m * 16 + lr * 4 + j], rs[m][j]);
    }
}

// ---------------------------------------------------------------------------
// Kernel 3: per_sample = d_ii/T + log(rowsum_i - exp(-d_ii/T)); mean over i.
// ---------------------------------------------------------------------------
__global__ __launch_bounds__(256) void finalize_kernel(
        const float* __restrict__ rowsum, const float* __restrict__ diag_dist,
        float* __restrict__ out) {
    const int tid = threadIdx.x;
    float s = 0.0f;
    for (int i = tid; i < BSZ; i += 256) {
        const float d   = diag_dist[i];
        const float num = __expf(-20.0f * d);
        const float den = rowsum[i] - num;
        s += (den != 0.0f) ? (20.0f * d + logf(den)) : 0.0f;
    }
    #pragma unroll
    for (int off = 32; off; off >>= 1) s += __shfl_down(s, off);

    __shared__ float lds[4];
    if ((tid & 63) == 0) lds[tid >> 6] = s;
    __syncthreads();
    if (tid == 0) out[0] = (lds[0] + lds[1] + lds[2] + lds[3]) * (1.0f / (float)BSZ);
}

// ---------------------------------------------------------------------------
extern "C" void kernel_launch(void* const* d_in, const int* in_sizes, int n_in,
                              void* d_out, int out_size, void* d_ws, size_t ws_size,
                              hipStream_t stream) {
    // setup_inputs() order: text_embeddings first, image_embeddings second.
    const float* txt = (const float*)d_in[0];
    const float* img = (const float*)d_in[1];
    float* out = (float*)d_out;

    u16* imgb = (u16*)d_ws;
    u16* txtb = imgb + (size_t)BSZ * DSZ;
    float* fws     = (float*)(txtb + (size_t)BSZ * DSZ);
    float* rowsum  = fws;             // [4096] zeroed inside cvt_norm
    float* diag    = fws + BSZ;       // [4096]
    float* img_sq  = fws + 2 * BSZ;   // [4096]
    float* txt_sq  = fws + 3 * BSZ;   // [4096]

    (void)hipFuncSetAttribute((const void*)fused_mfma_kernel,
                              hipFuncAttributeMaxDynamicSharedMemorySize, 131072);

    cvt_norm_kernel<<<2048, 256, 0, stream>>>(img, txt, imgb, txtb,
                                              img_sq, txt_sq, rowsum);

    fused_mfma_kernel<<<dim3(BSZ / BN, BSZ / BM), 512, 131072, stream>>>(
        imgb, txtb, img_sq, txt_sq, rowsum, diag);

    finalize_kernel<<<1, 256, 0, stream>>>(rowsum, diag, out);
}

// Round 10
// 130.871 us; speedup vs baseline: 1.1416x; 1.1416x over previous
//
#include <hip/hip_runtime.h>
#include <hip/hip_bf16.h>
#include <math.h>

#define BSZ 4096
#define DSZ 1024
#define BM  256
#define BN  256
#define BK  64
#define NT  16          // K-tiles
#define NIT 8           // iterations, 2 K-tiles each

typedef unsigned short u16;
typedef __attribute__((ext_vector_type(8))) short bf16x8;   // 8 bf16 = 4 VGPRs
typedef __attribute__((ext_vector_type(4))) float f32x4;    // mfma 16x16 accum

__device__ inline u16 f2bf_rne(float f) {
    unsigned int u = __float_as_uint(f);
    u += 0x7fffu + ((u >> 16) & 1u);      // round-to-nearest-even
    return (u16)(u >> 16);
}

// ---------------------------------------------------------------------------
// Kernel 1: fp32 -> bf16 + exact fp32 row norms. One wave per row.
// Also zeroes rowsum[] (ws is poisoned 0xAA before every launch).
// ---------------------------------------------------------------------------
__global__ __launch_bounds__(256) void cvt_norm_kernel(
        const float* __restrict__ img, const float* __restrict__ txt,
        u16* __restrict__ imgb, u16* __restrict__ txtb,
        float* __restrict__ img_sq, float* __restrict__ txt_sq,
        float* __restrict__ rowsum) {
    const int wid  = blockIdx.x * 4 + (threadIdx.x >> 6);   // 0..8191
    const int lane = threadIdx.x & 63;
    const bool isTxt = (wid >= BSZ);
    const int row = isTxt ? wid - BSZ : wid;

    const float* __restrict__ src = (isTxt ? txt : img) + (size_t)row * DSZ;
    u16* __restrict__ dst = (isTxt ? txtb : imgb) + (size_t)row * DSZ;

    float s = 0.0f;
    #pragma unroll
    for (int c = 0; c < 4; ++c) {
        const float4 v = *reinterpret_cast<const float4*>(src + c * 256 + lane * 4);
        ushort4 o;
        o.x = f2bf_rne(v.x); o.y = f2bf_rne(v.y);
        o.z = f2bf_rne(v.z); o.w = f2bf_rne(v.w);
        *reinterpret_cast<ushort4*>(dst + c * 256 + lane * 4) = o;
        s += v.x * v.x + v.y * v.y + v.z * v.z + v.w * v.w;
    }
    #pragma unroll
    for (int off = 32; off; off >>= 1) s += __shfl_xor(s, off);

    if (lane == 0) {
        if (isTxt) txt_sq[row] = s;
        else { img_sq[row] = s; rowsum[row] = 0.0f; }
    }
}

// ---------------------------------------------------------------------------
// Kernel 2: 256x256 bf16 MFMA cross-GEMM, 8-phase counted-vmcnt schedule.
// A-frag ping-pong PREFETCH only (B-frags read in-phase at q==0) — R9's
// bfr double-buffer spilled to scratch (WRITE_SIZE 4->22 MB, MfmaUtil 24->17);
// reverting it is this round's single change. Registers: 128 acc + ~120 arch
// fits the 256/wave cap (8 waves/CU).
//
// LDS 128 KB: A[buf2][half2][128 rows][8 chunks x 16B] @0, B same @65536.
// Tile parity == buffer parity. Swizzle (T2, rule #21): stored chunk s holds
// global chunk s^(row&7); read XORs the same. Verified: 0 conflicts.
//
// Stage schedule, iteration i (tiles t0=2i, t1=2i+1):
//   p0: A(2i+1).h1   p1: B(2i+2) [4]   p2: A(2i+2).h0
//   p4: A(2i+2).h1   p5: B(2i+3) [4]   p6: A(2i+3).h0
// vmcnt guards (ledger hand-traced; every half-tile formally drained before
// its first ds_read): steady p0->8, p2->6, p4->8, p6->6; prologue 6;
// last iter p0->8, p2->0.
// lgkm: every phase enters with <=4 outstanding (afr_next); q==0 issues
// bfr(8) then afr_next(4) -> wait lgkmcnt(4) covers bfr+afr_this. Last
// phase: lgkmcnt(0).
// ---------------------------------------------------------------------------
__global__ __launch_bounds__(512, 2) void fused_mfma_kernel(
        const u16* __restrict__ imgb, const u16* __restrict__ txtb,
        const float* __restrict__ img_sq, const float* __restrict__ txt_sq,
        float* __restrict__ rowsum, float* __restrict__ diag_dist) {

    extern __shared__ char smem[];           // 131072 bytes

    const int lin = blockIdx.y * 16 + blockIdx.x;
    const int sw  = (lin & 7) * 32 + (lin >> 3);   // bijective XCD swizzle
    const int bi = sw >> 4, bj = sw & 15;

    const int tid  = threadIdx.x;
    const int lane = tid & 63;
    const int w    = tid >> 6;               // wave 0..7
    const int wr   = w >> 2;                 // 0..1  M-half
    const int wc   = w & 3;                  // 0..3  N-quarter
    const int lr   = lane >> 4;              // 0..3
    const int lc   = lane & 15;
    const int swz  = lc & 7;                 // == row&7 for rows m*16+lc

    const int ib0 = bi * BM;
    const int jb0 = bj * BN;

    auto stageHT = [&](int mat, int kt, int h) {   // one half-tile: 2 loads/thr
        const u16* base   = mat ? txtb : imgb;
        const int rowbase = mat ? jb0 : ib0;
        const int xoff    = mat ? 65536 : 0;
        const int b = kt & 1;
        #pragma unroll
        for (int j = 0; j < 2; ++j) {
            const int row_h = j * 64 + (tid >> 3);        // 0..127 within half
            const int gch   = (tid & 7) ^ (row_h & 7);    // pre-swizzled src
            const u16* g = base + (size_t)(rowbase + h * 128 + row_h) * DSZ
                                + kt * BK + gch * 8;
            char* dst = smem + xoff + b * 32768 + h * 16384 + j * 8192 + w * 1024;
            __builtin_amdgcn_global_load_lds(
                (const __attribute__((address_space(1))) void*)g,
                (__attribute__((address_space(3))) void*)dst, 16, 0, 0);
        }
    };
    auto stageB = [&](int kt) { stageHT(1, kt, 0); stageHT(1, kt, 1); };

    const char* Ab[2] = { smem + wr * 16384,
                          smem + 32768 + wr * 16384 };
    const char* Bb[2] = { smem + 65536 + (wc >> 1) * 16384,
                          smem + 65536 + 32768 + (wc >> 1) * 16384 };
    const int rboff = (wc & 1) * 64;

    // ---- prologue: 14 loads; vmcnt(6) so B0 + A0.h0 + A0.h1 have landed ----
    stageB(0);                 // 4
    stageHT(0, 0, 0);          // 2
    stageHT(0, 0, 1);          // 2
    stageB(1);                 // 4
    stageHT(0, 1, 0);          // 2
    asm volatile("s_waitcnt vmcnt(6)" ::: "memory");
    __builtin_amdgcn_s_barrier();

    f32x4 acc[8][4] = {};
    bf16x8 bfr[2][4];          // [kk][n] — single set, read in-phase at q==0
    bf16x8 afr[2][2][2];       // [phase parity][dm][kk] — ping-pong prefetch

    // fragments for iter0/p0 (A tile 0, rows 0..31) — lgkm-waited at p0
    #pragma unroll
    for (int dm = 0; dm < 2; ++dm)
        #pragma unroll
        for (int kk = 0; kk < 2; ++kk)
            afr[0][dm][kk] = *reinterpret_cast<const bf16x8*>(
                Ab[0] + (dm * 16 + lc) * 128 + (((kk * 4 + lr) ^ swz) * 16));

    for (int i = 0; i < NIT; ++i) {
        const bool more = (i < NIT - 1);
        #pragma unroll
        for (int p = 0; p < 8; ++p) {
            const int tsel = p >> 2;             // tile of the pair (this phase)
            const int q    = p & 3;              // m-quadrant
            const int np   = (p + 1) & 7;        // next phase
            const int nq   = np & 3;
            const int ntsel = (p < 7) ? (np >> 2) : 0;
            const int nset  = (p + 1) & 1;
            const bool last_phase = (!more) && (p == 7);

            // ---- B-frags for THIS phase (q==0 only), before afr prefetch ----
            if (q == 0) {
                #pragma unroll
                for (int kk = 0; kk < 2; ++kk)
                    #pragma unroll
                    for (int n = 0; n < 4; ++n)
                        bfr[kk][n] = *reinterpret_cast<const bf16x8*>(
                            Bb[tsel] + (rboff + n * 16 + lc) * 128
                                     + (((kk * 4 + lr) ^ swz) * 16));
            }
            // ---- prefetch NEXT phase's A-frags (overlap this MFMA) ----
            if (!last_phase) {
                #pragma unroll
                for (int dm = 0; dm < 2; ++dm)
                    #pragma unroll
                    for (int kk = 0; kk < 2; ++kk)
                        afr[nset][dm][kk] = *reinterpret_cast<const bf16x8*>(
                            Ab[ntsel] + ((nq * 2 + dm) * 16 + lc) * 128
                                      + (((kk * 4 + lr) ^ swz) * 16));
            }

            // ---- stage one half-tile (sliding schedule) ----
            if (p == 0)      stageHT(0, 2 * i + 1, 1);
            else if (p == 1) { if (more) stageB(2 * i + 2); }
            else if (p == 2) { if (more) stageHT(0, 2 * i + 2, 0); }
            else if (p == 4) { if (more) stageHT(0, 2 * i + 2, 1); }
            else if (p == 5) { if (more) stageB(2 * i + 3); }
            else if (p == 6) { if (more) stageHT(0, 2 * i + 3, 0); }

            __builtin_amdgcn_sched_barrier(0);   // pin read+stage issue here
            __builtin_amdgcn_s_barrier();

            // counted lgkm: drain this phase's frags, keep afr_next in flight
            if (last_phase) asm volatile("s_waitcnt lgkmcnt(0)" ::: "memory");
            else            asm volatile("s_waitcnt lgkmcnt(4)" ::: "memory");
            __builtin_amdgcn_sched_barrier(0);   // rule #18

            __builtin_amdgcn_s_setprio(1);
            #pragma unroll
            for (int dm = 0; dm < 2; ++dm)
                #pragma unroll
                for (int n = 0; n < 4; ++n)
                    #pragma unroll
                    for (int kk = 0; kk < 2; ++kk)
                        acc[q * 2 + dm][n] = __builtin_amdgcn_mfma_f32_16x16x32_bf16(
                            afr[p & 1][dm][kk], bfr[kk][n],
                            acc[q * 2 + dm][n], 0, 0, 0);
            __builtin_amdgcn_s_setprio(0);

            // ---- counted vmcnt guards (ledger-verified) ----
            if ((p & 1) == 0) {
                if (more) {
                    if (p == 0 || p == 4)
                        asm volatile("s_waitcnt vmcnt(8)" ::: "memory");
                    else
                        asm volatile("s_waitcnt vmcnt(6)" ::: "memory");
                } else {
                    if (p == 0)
                        asm volatile("s_waitcnt vmcnt(8)" ::: "memory");
                    else if (p == 2)
                        asm volatile("s_waitcnt vmcnt(0)" ::: "memory");
                }
            }
            __builtin_amdgcn_s_barrier();
        }
    }

    // ---- epilogue: dist -> sim -> row partial sums + diagonal ----
    const int jw = jb0 + wc * 64;            // wave's first text col
    const int iw = ib0 + wr * 128;           // wave's first image row

    float tq[4];
    #pragma unroll
    for (int n = 0; n < 4; ++n) tq[n] = txt_sq[jw + n * 16 + lc];

    float rs[8][4];
    #pragma unroll
    for (int m = 0; m < 8; ++m) {
        #pragma unroll
        for (int j = 0; j < 4; ++j) {
            const int gi = iw + m * 16 + lr * 4 + j;
            const float iq = img_sq[gi];
            float s = 0.0f;
            #pragma unroll
            for (int n = 0; n < 4; ++n) {
                const float d2 = iq + tq[n] - 2.0f * acc[m][n][j];
                const float d  = sqrtf(fmaxf(d2, 0.0f));
                const float sim = __expf(-20.0f * d);
                s += sim;
                if (gi == jw + n * 16 + lc) diag_dist[gi] = d;
            }
            rs[m][j] = s;
        }
    }

    #pragma unroll
    for (int off = 1; off < 16; off <<= 1)
        #pragma unroll
        for (int m = 0; m < 8; ++m)
            #pragma unroll
            for (int j = 0; j < 4; ++j)
                rs[m][j] += __shfl_xor(rs[m][j], off);

    if (lc == 0) {
        #pragma unroll
        for (int m = 0; m < 8; ++m)
            #pragma unroll
            for (int j = 0; j < 4; ++j)
                atomicAdd(&rowsum[iw + m * 16 + lr * 4 + j], rs[m][j]);
    }
}

// ---------------------------------------------------------------------------
// Kernel 3: per_sample = d_ii/T + log(rowsum_i - exp(-d_ii/T)); mean over i.
// ---------------------------------------------------------------------------
__global__ __launch_bounds__(256) void finalize_kernel(
        const float* __restrict__ rowsum, const float* __restrict__ diag_dist,
        float* __restrict__ out) {
    const int tid = threadIdx.x;
    float s = 0.0f;
    for (int i = tid; i < BSZ; i += 256) {
        const float d   = diag_dist[i];
        const float num = __expf(-20.0f * d);
        const float den = rowsum[i] - num;
        s += (den != 0.0f) ? (20.0f * d + logf(den)) : 0.0f;
    }
    #pragma unroll
    for (int off = 32; off; off >>= 1) s += __shfl_down(s, off);

    __shared__ float lds[4];
    if ((tid & 63) == 0) lds[tid >> 6] = s;
    __syncthreads();
    if (tid == 0) out[0] = (lds[0] + lds[1] + lds[2] + lds[3]) * (1.0f / (float)BSZ);
}

// ---------------------------------------------------------------------------
extern "C" void kernel_launch(void* const* d_in, const int* in_sizes, int n_in,
                              void* d_out, int out_size, void* d_ws, size_t ws_size,
                              hipStream_t stream) {
    // setup_inputs() order: text_embeddings first, image_embeddings second.
    const float* txt = (const float*)d_in[0];
    const float* img = (const float*)d_in[1];
    float* out = (float*)d_out;

    u16* imgb = (u16*)d_ws;
    u16* txtb = imgb + (size_t)BSZ * DSZ;
    float* fws     = (float*)(txtb + (size_t)BSZ * DSZ);
    float* rowsum  = fws;             // [4096] zeroed inside cvt_norm
    float* diag    = fws + BSZ;       // [4096]
    float* img_sq  = fws + 2 * BSZ;   // [4096]
    float* txt_sq  = fws + 3 * BSZ;   // [4096]

    (void)hipFuncSetAttribute((const void*)fused_mfma_kernel,
                              hipFuncAttributeMaxDynamicSharedMemorySize, 131072);

    cvt_norm_kernel<<<2048, 256, 0, stream>>>(img, txt, imgb, txtb,
                                              img_sq, txt_sq, rowsum);

    fused_mfma_kernel<<<dim3(BSZ / BN, BSZ / BM), 512, 131072, stream>>>(
        imgb, txtb, img_sq, txt_sq, rowsum, diag);

    finalize_kernel<<<1, 256, 0, stream>>>(rowsum, diag, out);
}

// Round 11
// 127.727 us; speedup vs baseline: 1.1697x; 1.0246x over previous
//
#include <hip/hip_runtime.h>
#include <hip/hip_bf16.h>
#include <math.h>

#define BSZ 4096
#define DSZ 1024
#define BM  256
#define BN  256
#define BK  64
#define NT  16          // K-tiles
#define NIT 8           // iterations, 2 K-tiles each

typedef unsigned short u16;
typedef __attribute__((ext_vector_type(8))) short bf16x8;   // 8 bf16 = 4 VGPRs
typedef __attribute__((ext_vector_type(4))) float f32x4;    // mfma 16x16 accum

__device__ inline u16 f2bf_rne(float f) {
    unsigned int u = __float_as_uint(f);
    u += 0x7fffu + ((u >> 16) & 1u);      // round-to-nearest-even
    return (u16)(u >> 16);
}

// ---------------------------------------------------------------------------
// Kernel 1: fp32 -> bf16 + exact fp32 row norms. One wave per row.
// Also zeroes rowsum[] (ws is poisoned 0xAA before every launch).
// ---------------------------------------------------------------------------
__global__ __launch_bounds__(256) void cvt_norm_kernel(
        const float* __restrict__ img, const float* __restrict__ txt,
        u16* __restrict__ imgb, u16* __restrict__ txtb,
        float* __restrict__ img_sq, float* __restrict__ txt_sq,
        float* __restrict__ rowsum) {
    const int wid  = blockIdx.x * 4 + (threadIdx.x >> 6);   // 0..8191
    const int lane = threadIdx.x & 63;
    const bool isTxt = (wid >= BSZ);
    const int row = isTxt ? wid - BSZ : wid;

    const float* __restrict__ src = (isTxt ? txt : img) + (size_t)row * DSZ;
    u16* __restrict__ dst = (isTxt ? txtb : imgb) + (size_t)row * DSZ;

    float s = 0.0f;
    #pragma unroll
    for (int c = 0; c < 4; ++c) {
        const float4 v = *reinterpret_cast<const float4*>(src + c * 256 + lane * 4);
        ushort4 o;
        o.x = f2bf_rne(v.x); o.y = f2bf_rne(v.y);
        o.z = f2bf_rne(v.z); o.w = f2bf_rne(v.w);
        *reinterpret_cast<ushort4*>(dst + c * 256 + lane * 4) = o;
        s += v.x * v.x + v.y * v.y + v.z * v.z + v.w * v.w;
    }
    #pragma unroll
    for (int off = 32; off; off >>= 1) s += __shfl_xor(s, off);

    if (lane == 0) {
        if (isTxt) txt_sq[row] = s;
        else { img_sq[row] = s; rowsum[row] = 0.0f; }
    }
}

// ---------------------------------------------------------------------------
// Kernel 2: 256x256 bf16 MFMA cross-GEMM, m201-faithful 8-phase schedule:
// NO sched_barrier pins, NO frag double-buffering, 2 vmcnt guards / 8 phases.
// (R6/R10 post-mortem: per-phase pins + per-even-phase guards held us at
// ~55 us / MfmaUtil 23%; m141 evidence: order-pinning defeats the compiler.)
// 512 thr = 8 waves (2M x 4N); per-wave 128x64 = acc[8][4]. Grid 16x16.
//
// LDS 128 KB: A[buf2][half2][128 rows][8 chunks x 16B] @0, B same @65536.
// Buffer = tile parity. Swizzle (T2, rule #21): stored chunk s holds global
// chunk s^(row&7); read applies the same XOR. Verified: 0 conflicts.
//
// RACE-FREE stage schedule (fixes R6/R10 latent race where A(2i+2).h0 was
// staged at p2 while p3 still read the same buffer): every stage is issued
// only after the barrier that postdates the prior tenant's last read.
//   p0: A(2i+1) h0+h1 [buf1 free after prev p7]   (4 loads)
//   p1: B(2i+2)       [buf0 B free after p0]      (4)
//   p4: A(2i+2).h0    [buf0 A free after p3]      (2)
//   p5: A(2i+2).h1                                (2)
//   p6: B(2i+3)       [buf1 B free after p4]      (4)
// Ledger (hand-traced): guards vmcnt(4) at p3-end (drains B(2i+1)+A(2i+1)
// for p4) and p7-end (drains B(2i+2)+A(2i+2) for next p0). Prologue:
// B(0),A(0),B(1) then vmcnt(4). Last iter: p3-end vmcnt(0), no p7 guard.
//
// Phase body: frag ds_reads (q==0: +8 B-frags) -> stage -> s_barrier ->
// lgkmcnt(0) -> setprio(1) 16 MFMA setprio(0) -> [guard] -> s_barrier.
// ---------------------------------------------------------------------------
__global__ __launch_bounds__(512, 2) void fused_mfma_kernel(
        const u16* __restrict__ imgb, const u16* __restrict__ txtb,
        const float* __restrict__ img_sq, const float* __restrict__ txt_sq,
        float* __restrict__ rowsum, float* __restrict__ diag_dist) {

    extern __shared__ char smem[];           // 131072 bytes

    const int lin = blockIdx.y * 16 + blockIdx.x;
    const int sw  = (lin & 7) * 32 + (lin >> 3);   // bijective XCD swizzle
    const int bi = sw >> 4, bj = sw & 15;

    const int tid  = threadIdx.x;
    const int lane = tid & 63;
    const int w    = tid >> 6;               // wave 0..7
    const int wr   = w >> 2;                 // 0..1  M-half
    const int wc   = w & 3;                  // 0..3  N-quarter
    const int lr   = lane >> 4;              // 0..3
    const int lc   = lane & 15;
    const int swz  = lc & 7;                 // == row&7 for rows m*16+lc

    const int ib0 = bi * BM;
    const int jb0 = bj * BN;

    auto stageHT = [&](int mat, int kt, int h) {   // one half-tile: 2 loads/thr
        const u16* base   = mat ? txtb : imgb;
        const int rowbase = mat ? jb0 : ib0;
        const int xoff    = mat ? 65536 : 0;
        const int b = kt & 1;
        #pragma unroll
        for (int j = 0; j < 2; ++j) {
            const int row_h = j * 64 + (tid >> 3);        // 0..127 within half
            const int gch   = (tid & 7) ^ (row_h & 7);    // pre-swizzled src
            const u16* g = base + (size_t)(rowbase + h * 128 + row_h) * DSZ
                                + kt * BK + gch * 8;
            char* dst = smem + xoff + b * 32768 + h * 16384 + j * 8192 + w * 1024;
            __builtin_amdgcn_global_load_lds(
                (const __attribute__((address_space(1))) void*)g,
                (__attribute__((address_space(3))) void*)dst, 16, 0, 0);
        }
    };
    auto stageA = [&](int kt) { stageHT(0, kt, 0); stageHT(0, kt, 1); };
    auto stageB = [&](int kt) { stageHT(1, kt, 0); stageHT(1, kt, 1); };

    const char* Ab[2] = { smem + wr * 16384,
                          smem + 32768 + wr * 16384 };
    const char* Bb[2] = { smem + 65536 + (wc >> 1) * 16384,
                          smem + 65536 + 32768 + (wc >> 1) * 16384 };
    const int rboff = (wc & 1) * 64;

    // ---- prologue: B(0), A(0), B(1) = 12 loads; drain t0 (8 oldest) ----
    stageB(0);                 // 4
    stageA(0);                 // 4
    stageB(1);                 // 4
    asm volatile("s_waitcnt vmcnt(4)" ::: "memory");
    __builtin_amdgcn_s_barrier();

    f32x4 acc[8][4] = {};
    bf16x8 bfr[2][4];          // [kk][n] — read at q==0, live 4 phases

    for (int i = 0; i < NIT; ++i) {
        const bool more = (i < NIT - 1);
        #pragma unroll
        for (int p = 0; p < 8; ++p) {
            const int tsel = p >> 2;             // tile of the pair
            const int q    = p & 3;              // m-quadrant

            // ---- this phase's fragment reads (compiler-scheduled) ----
            if (q == 0) {
                #pragma unroll
                for (int kk = 0; kk < 2; ++kk)
                    #pragma unroll
                    for (int n = 0; n < 4; ++n)
                        bfr[kk][n] = *reinterpret_cast<const bf16x8*>(
                            Bb[tsel] + (rboff + n * 16 + lc) * 128
                                     + (((kk * 4 + lr) ^ swz) * 16));
            }
            bf16x8 afr[2][2];
            #pragma unroll
            for (int dm = 0; dm < 2; ++dm)
                #pragma unroll
                for (int kk = 0; kk < 2; ++kk)
                    afr[dm][kk] = *reinterpret_cast<const bf16x8*>(
                        Ab[tsel] + ((q * 2 + dm) * 16 + lc) * 128
                                 + (((kk * 4 + lr) ^ swz) * 16));

            // ---- stage (race-free slots) ----
            if (p == 0)      stageA(2 * i + 1);
            else if (p == 1) { if (more) stageB(2 * i + 2); }
            else if (p == 4) { if (more) stageHT(0, 2 * i + 2, 0); }
            else if (p == 5) { if (more) stageHT(0, 2 * i + 2, 1); }
            else if (p == 6) { if (more) stageB(2 * i + 3); }

            __builtin_amdgcn_s_barrier();
            asm volatile("s_waitcnt lgkmcnt(0)" ::: "memory");

            __builtin_amdgcn_s_setprio(1);
            #pragma unroll
            for (int dm = 0; dm < 2; ++dm)
                #pragma unroll
                for (int n = 0; n < 4; ++n)
                    #pragma unroll
                    for (int kk = 0; kk < 2; ++kk)
                        acc[q * 2 + dm][n] = __builtin_amdgcn_mfma_f32_16x16x32_bf16(
                            afr[dm][kk], bfr[kk][n], acc[q * 2 + dm][n], 0, 0, 0);
            __builtin_amdgcn_s_setprio(0);

            // ---- counted guards: only p3 / p7 (m201 cadence) ----
            if (p == 3) {
                if (more) asm volatile("s_waitcnt vmcnt(4)" ::: "memory");
                else      asm volatile("s_waitcnt vmcnt(0)" ::: "memory");
            } else if (p == 7) {
                if (more) asm volatile("s_waitcnt vmcnt(4)" ::: "memory");
            }
            __builtin_amdgcn_s_barrier();
        }
    }

    // ---- epilogue: dist -> sim -> row partial sums + diagonal ----
    const int jw = jb0 + wc * 64;            // wave's first text col
    const int iw = ib0 + wr * 128;           // wave's first image row

    float tq[4];
    #pragma unroll
    for (int n = 0; n < 4; ++n) tq[n] = txt_sq[jw + n * 16 + lc];

    float rs[8][4];
    #pragma unroll
    for (int m = 0; m < 8; ++m) {
        #pragma unroll
        for (int j = 0; j < 4; ++j) {
            const int gi = iw + m * 16 + lr * 4 + j;
            const float iq = img_sq[gi];
            float s = 0.0f;
            #pragma unroll
            for (int n = 0; n < 4; ++n) {
                const float d2 = iq + tq[n] - 2.0f * acc[m][n][j];
                const float d  = sqrtf(fmaxf(d2, 0.0f));
                const float sim = __expf(-20.0f * d);
                s += sim;
                if (gi == jw + n * 16 + lc) diag_dist[gi] = d;
            }
            rs[m][j] = s;
        }
    }

    #pragma unroll
    for (int off = 1; off < 16; off <<= 1)
        #pragma unroll
        for (int m = 0; m < 8; ++m)
            #pragma unroll
            for (int j = 0; j < 4; ++j)
                rs[m][j] += __shfl_xor(rs[m][j], off);

    if (lc == 0) {
        #pragma unroll
        for (int m = 0; m < 8; ++m)
            #pragma unroll
            for (int j = 0; j < 4; ++j)
                atomicAdd(&rowsum[iw + m * 16 + lr * 4 + j], rs[m][j]);
    }
}

// ---------------------------------------------------------------------------
// Kernel 3: per_sample = d_ii/T + log(rowsum_i - exp(-d_ii/T)); mean over i.
// ---------------------------------------------------------------------------
__global__ __launch_bounds__(256) void finalize_kernel(
        const float* __restrict__ rowsum, const float* __restrict__ diag_dist,
        float* __restrict__ out) {
    const int tid = threadIdx.x;
    float s = 0.0f;
    for (int i = tid; i < BSZ; i += 256) {
        const float d   = diag_dist[i];
        const float num = __expf(-20.0f * d);
        const float den = rowsum[i] - num;
        s += (den != 0.0f) ? (20.0f * d + logf(den)) : 0.0f;
    }
    #pragma unroll
    for (int off = 32; off; off >>= 1) s += __shfl_down(s, off);

    __shared__ float lds[4];
    if ((tid & 63) == 0) lds[tid >> 6] = s;
    __syncthreads();
    if (tid == 0) out[0] = (lds[0] + lds[1] + lds[2] + lds[3]) * (1.0f / (float)BSZ);
}

// ---------------------------------------------------------------------------
extern "C" void kernel_launch(void* const* d_in, const int* in_sizes, int n_in,
                              void* d_out, int out_size, void* d_ws, size_t ws_size,
                              hipStream_t stream) {
    // setup_inputs() order: text_embeddings first, image_embeddings second.
    const float* txt = (const float*)d_in[0];
    const float* img = (const float*)d_in[1];
    float* out = (float*)d_out;

    u16* imgb = (u16*)d_ws;
    u16* txtb = imgb + (size_t)BSZ * DSZ;
    float* fws     = (float*)(txtb + (size_t)BSZ * DSZ);
    float* rowsum  = fws;             // [4096] zeroed inside cvt_norm
    float* diag    = fws + BSZ;       // [4096]
    float* img_sq  = fws + 2 * BSZ;   // [4096]
    float* txt_sq  = fws + 3 * BSZ;   // [4096]

    (void)hipFuncSetAttribute((const void*)fused_mfma_kernel,
                              hipFuncAttributeMaxDynamicSharedMemorySize, 131072);

    cvt_norm_kernel<<<2048, 256, 0, stream>>>(img, txt, imgb, txtb,
                                              img_sq, txt_sq, rowsum);

    fused_mfma_kernel<<<dim3(BSZ / BN, BSZ / BM), 512, 131072, stream>>>(
        imgb, txtb, img_sq, txt_sq, rowsum, diag);

    finalize_kernel<<<1, 256, 0, stream>>>(rowsum, diag, out);
}